// Round 1
// baseline (108.481 us; speedup 1.0000x reference)
//
#include <hip/hip_runtime.h>
#include <math.h>

// Soft-DTW (DILATE, alpha=1, gamma=0.01), B=64, N=512, F=1, n=511.
// R19: single-wave-per-batch restructure. One block = ONE wave (64 lanes);
// lane l owns DP rows 8l..8l+7. No inter-wave pipeline: no mailbox, no
// flags, no spin, no barriers in the main loop. 1024 diagonal steps flat
// (vs 1120 pipeline step-slots in the 4-wave R18 design), and the
// cross-lane DPP shift happens once per 8 rows instead of once per 2
// (dependent ops/diagonal 2.5 -> 2.25 along the DP zigzag).
//
// Recursion per diagonal d (s = d-2 = 0..1023), cell c=0..7 (row 8l+c):
//   nv[c] = (dy[c] - dx[j-1])^2 + min3(prev2[c-1], prev1[c-1], prev1[c])
// where prevK[x] = row 8l+x at diag d-K; for c==0 the (c-1) terms come
// from the neighbor lane's row 8l-1 via SH2 (carried) and sh1 = DPP shift
// of r1_7. Lane 0 injects INF; the R[0][0]=0 seed rides r2_0 (consumed
// exactly once by cell (1,1) at d=2). Invalid cells stay ~INF by
// construction (ulp(1e9)=64 absorbs u^2 increments; drift bounded).
//
// dx window: per chunk of 32 diagonals each lane needs 39 contiguous dx
// values (window idx w = k+7-c). Kept in 40 registers, double-buffered
// (xa/xb), loaded as 20x ds_read_b64. Per-lane stride is 8 floats (32B)
// => naive layout would be a 16-way bank conflict; dxe is replicated 4x
// at stride 1546 floats (== +10 banks), lane uses replica (l>>2)&3 =>
// all 16 lanes of a conflict group land on distinct banks (residual
// 4-way across l,l+16,l+32,l+48 = wave64 b64 floor).

#define INF_F 1000000000.0f

// whole-wave shift right by 1; lane0 receives `oldv` (bound_ctrl=0 keeps old)
__device__ __forceinline__ float dpp_shr1_inj(float x, float oldv){
  int r = __builtin_amdgcn_update_dpp(__float_as_int(oldv), __float_as_int(x),
                                      0x138 /*WAVE_SHR1*/, 0xf, 0xf, false);
  return __int_as_float(r);
}
__device__ __forceinline__ float min3f(float a, float b, float c){
  float d;
  asm("v_min3_f32 %0, %1, %2, %3" : "=v"(d) : "v"(a), "v"(b), "v"(c));
  return d;
}

// load 40-float window (20 float2, even-aligned) into P##0..P##39
#define LOADW40(P, FB) { const float2* _p = dxw + (FB); \
  float2 a0=_p[0],a1=_p[1],a2=_p[2],a3=_p[3],a4=_p[4],a5=_p[5],a6=_p[6],a7=_p[7]; \
  float2 a8=_p[8],a9=_p[9],a10=_p[10],a11=_p[11],a12=_p[12],a13=_p[13]; \
  float2 a14=_p[14],a15=_p[15],a16=_p[16],a17=_p[17],a18=_p[18],a19=_p[19]; \
  P##0=a0.x;  P##1=a0.y;  P##2=a1.x;  P##3=a1.y;  P##4=a2.x;  P##5=a2.y; \
  P##6=a3.x;  P##7=a3.y;  P##8=a4.x;  P##9=a4.y;  P##10=a5.x; P##11=a5.y; \
  P##12=a6.x; P##13=a6.y; P##14=a7.x; P##15=a7.y; P##16=a8.x; P##17=a8.y; \
  P##18=a9.x; P##19=a9.y; P##20=a10.x;P##21=a10.y;P##22=a11.x;P##23=a11.y; \
  P##24=a12.x;P##25=a12.y;P##26=a13.x;P##27=a13.y;P##28=a14.x;P##29=a14.y; \
  P##30=a15.x;P##31=a15.y;P##32=a16.x;P##33=a16.y;P##34=a17.x;P##35=a17.y; \
  P##36=a18.x;P##37=a18.y;P##38=a19.x;P##39=a19.y; }

// One diagonal, eight cells. W0..W7 = dx window value for cell 0..7
// (cell c uses window index K+7-c).
#define STEP8(K, W0, W1, W2, W3, W4, W5, W6, W7) { \
  float sh1 = dpp_shr1_inj(r1_7, INF_F); \
  float u0 = dy0 - (W0); float u1 = dy1 - (W1); \
  float u2 = dy2 - (W2); float u3 = dy3 - (W3); \
  float u4 = dy4 - (W4); float u5 = dy5 - (W5); \
  float u6 = dy6 - (W6); float u7 = dy7 - (W7); \
  float nv0 = fmaf(u0, u0, min3f(SH2,  sh1,  r1_0)); \
  float nv1 = fmaf(u1, u1, min3f(r2_0, r1_0, r1_1)); \
  float nv2 = fmaf(u2, u2, min3f(r2_1, r1_1, r1_2)); \
  float nv3 = fmaf(u3, u3, min3f(r2_2, r1_2, r1_3)); \
  float nv4 = fmaf(u4, u4, min3f(r2_3, r1_3, r1_4)); \
  float nv5 = fmaf(u5, u5, min3f(r2_4, r1_4, r1_5)); \
  float nv6 = fmaf(u6, u6, min3f(r2_5, r1_5, r1_6)); \
  float nv7 = fmaf(u7, u7, min3f(r2_6, r1_6, r1_7)); \
  if ((K) == 28) { if (cc == 31) ans = nv7; } \
  SH2 = sh1; \
  r2_0 = r1_0; r2_1 = r1_1; r2_2 = r1_2; r2_3 = r1_3; \
  r2_4 = r1_4; r2_5 = r1_5; r2_6 = r1_6; \
  r1_0 = nv0; r1_1 = nv1; r1_2 = nv2; r1_3 = nv3; \
  r1_4 = nv4; r1_5 = nv5; r1_6 = nv6; r1_7 = nv7; }

#define CHUNK(C, XU, XP) { \
  const int cc = (C); \
  if (cc < 31) { LOADW40(XP, fb0 + 16 * (cc + 1)); } \
  STEP8(0,  XU##7,  XU##6,  XU##5,  XU##4,  XU##3,  XU##2,  XU##1,  XU##0 ) \
  STEP8(1,  XU##8,  XU##7,  XU##6,  XU##5,  XU##4,  XU##3,  XU##2,  XU##1 ) \
  STEP8(2,  XU##9,  XU##8,  XU##7,  XU##6,  XU##5,  XU##4,  XU##3,  XU##2 ) \
  STEP8(3,  XU##10, XU##9,  XU##8,  XU##7,  XU##6,  XU##5,  XU##4,  XU##3 ) \
  STEP8(4,  XU##11, XU##10, XU##9,  XU##8,  XU##7,  XU##6,  XU##5,  XU##4 ) \
  STEP8(5,  XU##12, XU##11, XU##10, XU##9,  XU##8,  XU##7,  XU##6,  XU##5 ) \
  STEP8(6,  XU##13, XU##12, XU##11, XU##10, XU##9,  XU##8,  XU##7,  XU##6 ) \
  STEP8(7,  XU##14, XU##13, XU##12, XU##11, XU##10, XU##9,  XU##8,  XU##7 ) \
  STEP8(8,  XU##15, XU##14, XU##13, XU##12, XU##11, XU##10, XU##9,  XU##8 ) \
  STEP8(9,  XU##16, XU##15, XU##14, XU##13, XU##12, XU##11, XU##10, XU##9 ) \
  STEP8(10, XU##17, XU##16, XU##15, XU##14, XU##13, XU##12, XU##11, XU##10) \
  STEP8(11, XU##18, XU##17, XU##16, XU##15, XU##14, XU##13, XU##12, XU##11) \
  STEP8(12, XU##19, XU##18, XU##17, XU##16, XU##15, XU##14, XU##13, XU##12) \
  STEP8(13, XU##20, XU##19, XU##18, XU##17, XU##16, XU##15, XU##14, XU##13) \
  STEP8(14, XU##21, XU##20, XU##19, XU##18, XU##17, XU##16, XU##15, XU##14) \
  STEP8(15, XU##22, XU##21, XU##20, XU##19, XU##18, XU##17, XU##16, XU##15) \
  STEP8(16, XU##23, XU##22, XU##21, XU##20, XU##19, XU##18, XU##17, XU##16) \
  STEP8(17, XU##24, XU##23, XU##22, XU##21, XU##20, XU##19, XU##18, XU##17) \
  STEP8(18, XU##25, XU##24, XU##23, XU##22, XU##21, XU##20, XU##19, XU##18) \
  STEP8(19, XU##26, XU##25, XU##24, XU##23, XU##22, XU##21, XU##20, XU##19) \
  STEP8(20, XU##27, XU##26, XU##25, XU##24, XU##23, XU##22, XU##21, XU##20) \
  STEP8(21, XU##28, XU##27, XU##26, XU##25, XU##24, XU##23, XU##22, XU##21) \
  STEP8(22, XU##29, XU##28, XU##27, XU##26, XU##25, XU##24, XU##23, XU##22) \
  STEP8(23, XU##30, XU##29, XU##28, XU##27, XU##26, XU##25, XU##24, XU##23) \
  STEP8(24, XU##31, XU##30, XU##29, XU##28, XU##27, XU##26, XU##25, XU##24) \
  STEP8(25, XU##32, XU##31, XU##30, XU##29, XU##28, XU##27, XU##26, XU##25) \
  STEP8(26, XU##33, XU##32, XU##31, XU##30, XU##29, XU##28, XU##27, XU##26) \
  STEP8(27, XU##34, XU##33, XU##32, XU##31, XU##30, XU##29, XU##28, XU##27) \
  STEP8(28, XU##35, XU##34, XU##33, XU##32, XU##31, XU##30, XU##29, XU##28) \
  STEP8(29, XU##36, XU##35, XU##34, XU##33, XU##32, XU##31, XU##30, XU##29) \
  STEP8(30, XU##37, XU##36, XU##35, XU##34, XU##33, XU##32, XU##31, XU##30) \
  STEP8(31, XU##38, XU##37, XU##36, XU##35, XU##34, XU##33, XU##32, XU##31) }

__global__ __launch_bounds__(64, 1)
void sdtw_kernel(const float* __restrict__ input,
                 const float* __restrict__ target,
                 float* __restrict__ out) {
  const int b = blockIdx.x;
  const int t = threadIdx.x;          // lane 0..63; rows 8t .. 8t+7

  // dx table, 4 bank-rotated replicas. dxe[r*1546 + 512 + m] = dx[m],
  // m in [0,510]; zero-padded elsewhere. 1546 mod 32 == 10 => replica r
  // shifts banks by 10r.
  __shared__ __align__(8) float dxe[4 * 1546];

  const float* __restrict__ inp = input + b * 512;
  const float* __restrict__ tgt = target + b * 512;

  for (int rr = 0; rr < 4; ++rr)
    for (int i = t; i < 1546; i += 64) {
      float v = 0.0f;
      if (i >= 512 && i <= 1022) v = inp[i - 511] - inp[i - 512];
      dxe[rr * 1546 + i] = v;
    }

  // dy for the 8 owned rows (row 8t+c uses dy index 8t+c-1)
  const int rb = 8 * t;
  float dy0 = (t == 0) ? 0.0f : tgt[rb]     - tgt[rb - 1];
  float dy1 = tgt[rb + 1] - tgt[rb];
  float dy2 = tgt[rb + 2] - tgt[rb + 1];
  float dy3 = tgt[rb + 3] - tgt[rb + 2];
  float dy4 = tgt[rb + 4] - tgt[rb + 3];
  float dy5 = tgt[rb + 5] - tgt[rb + 4];
  float dy6 = tgt[rb + 6] - tgt[rb + 5];
  float dy7 = tgt[rb + 7] - tgt[rb + 6];

  // DP state: r1_* = rows @ diag d-1, r2_* = rows 0..6 @ diag d-2,
  // SH2 = neighbor row (8t-1) @ diag d-2. Seed R[0][0]=0 rides r2_0.
  float r1_0 = INF_F, r1_1 = INF_F, r1_2 = INF_F, r1_3 = INF_F;
  float r1_4 = INF_F, r1_5 = INF_F, r1_6 = INF_F, r1_7 = INF_F;
  float r2_0 = (t == 0) ? 0.0f : INF_F;
  float r2_1 = INF_F, r2_2 = INF_F, r2_3 = INF_F;
  float r2_4 = INF_F, r2_5 = INF_F, r2_6 = INF_F;
  float SH2 = INF_F;
  float ans = INF_F;

  float xa0,xa1,xa2,xa3,xa4,xa5,xa6,xa7,xa8,xa9,xa10,xa11,xa12,xa13,xa14,xa15;
  float xa16,xa17,xa18,xa19,xa20,xa21,xa22,xa23,xa24,xa25,xa26,xa27,xa28,xa29;
  float xa30,xa31,xa32,xa33,xa34,xa35,xa36,xa37,xa38,xa39;
  float xb0,xb1,xb2,xb3,xb4,xb5,xb6,xb7,xb8,xb9,xb10,xb11,xb12,xb13,xb14,xb15;
  float xb16,xb17,xb18,xb19,xb20,xb21,xb22,xb23,xb24,xb25,xb26,xb27,xb28,xb29;
  float xb30,xb31,xb32,xb33,xb34,xb35,xb36,xb37,xb38,xb39;

  // Window base (float2 units): lane t, chunk cc reads float2
  // [fb0 + 16*cc, +20) of its replica. Float index w of the window maps
  // to dx[m], m = 32*cc - 8t - 6 + w; step k cell c uses w = k+7-c.
  const float2* dxw = ((const float2*)dxe) + 773 * ((t >> 2) & 3);
  const int fb0 = 253 - 4 * t;

  __syncthreads();                    // staging visible; only barrier

  LOADW40(xa, fb0);                   // chunk 0 window

#pragma unroll 1
  for (int c = 0; c < 32; c += 2) {
    CHUNK(c,     xa, xb)
    CHUNK(c + 1, xb, xa)
  }

  // ans captured at chunk 31, step 28 (diag 1022) from row 511 = lane63.c7
  if (t == 63) {
    atomicAdd(out, ans * (1.0f / 64.0f));
  }
}

extern "C" void kernel_launch(void* const* d_in, const int* in_sizes, int n_in,
                              void* d_out, int out_size, void* d_ws, size_t ws_size,
                              hipStream_t stream) {
  const float* input  = (const float*)d_in[0];
  const float* target = (const float*)d_in[1];
  float* out = (float*)d_out;

  hipMemsetAsync(out, 0, sizeof(float), stream);
  sdtw_kernel<<<64, 64, 0, stream>>>(input, target, out);
}